// Round 15
// baseline (37.854 us; speedup 1.0000x reference)
//
#include <hip/hip_runtime.h>

#define N_FFT    1024
#define HOP      256
#define BATCH    16
#define T_LEN    262144
#define PAD      512
#define N_FRAMES 1025
#define N_FREQ   513
#define FPB      8
#define NTILES   129        // ceil(1025/8)

// output staging tile: stride 9 + skew (conflict-free extract, ~2-way flush)
#define OTI(f) ((f) * 9 + ((f) >> 4))
#define OT_SZ  (OTI(512) + 9)          // 4649 floats
// skew for the wave-private transpose scratch (2-way max on write & read)
#define SKA(p) ((p) + ((p) >> 5))

typedef float f32x2 __attribute__((ext_vector_type(2)));

__device__ __forceinline__ f32x2 mk2(float a, float b) { f32x2 r; r.x = a; r.y = b; return r; }

__device__ constexpr int   R4_[16] = {0,8,4,12,2,10,6,14,1,9,5,13,3,11,7,15}; // rev4
__device__ constexpr float CA_[16] = {   // cos(2*pi*k/16)
     1.0f,           0.92387953251f,  0.70710678119f,  0.38268343236f,
     0.0f,          -0.38268343236f, -0.70710678119f, -0.92387953251f,
    -1.0f,          -0.92387953251f, -0.70710678119f, -0.38268343236f,
     0.0f,           0.38268343236f,  0.70710678119f,  0.92387953251f};
__device__ constexpr float SA_[16] = {   // sin(2*pi*k/16)
     0.0f,           0.38268343236f,  0.70710678119f,  0.92387953251f,
     1.0f,           0.92387953251f,  0.70710678119f,  0.38268343236f,
     0.0f,          -0.38268343236f, -0.70710678119f, -0.92387953251f,
    -1.0f,          -0.92387953251f, -0.70710678119f, -0.38268343236f};
__device__ constexpr float C32_[16] = {  // cos(2*pi*j/32)
     1.0f,           0.98078528040f,  0.92387953251f,  0.83146961230f,
     0.70710678119f, 0.55557023302f,  0.38268343236f,  0.19509032202f,
     0.0f,          -0.19509032202f, -0.38268343236f, -0.55557023302f,
    -0.70710678119f,-0.83146961230f, -0.92387953251f, -0.98078528040f};
__device__ constexpr float S32_[16] = {  // sin(2*pi*j/32)
     0.0f,           0.19509032202f,  0.38268343236f,  0.55557023302f,
     0.70710678119f, 0.83146961230f,  0.92387953251f,  0.98078528040f,
     1.0f,           0.98078528040f,  0.92387953251f,  0.83146961230f,
     0.70710678119f, 0.55557023302f,  0.38268343236f,  0.19509032202f};
__device__ constexpr float C64_[16] = {  // cos(2*pi*j/64)
     1.0f,           0.99518472667f,  0.98078528040f,  0.95694033573f,
     0.92387953251f, 0.88192126435f,  0.83146961230f,  0.77301045336f,
     0.70710678119f, 0.63439328416f,  0.55557023302f,  0.47139673683f,
     0.38268343236f, 0.29028467725f,  0.19509032202f,  0.09801714033f};
__device__ constexpr float S64_[16] = {  // sin(2*pi*j/64)
     0.0f,           0.09801714033f,  0.19509032202f,  0.29028467725f,
     0.38268343236f, 0.47139673683f,  0.55557023302f,  0.63439328416f,
     0.70710678119f, 0.77301045336f,  0.83146961230f,  0.88192126435f,
     0.92387953251f, 0.95694033573f,  0.98078528040f,  0.99518472667f};

// Block = (batch, 8-frame tile), 256 threads = 4 waves; wave wv owns frames
// (t0+2wv, t0+2wv+1) packed via the symmetric-sequence trick:
// s[n] = 0.5*w[n]*(x[p+n]+x[p+m]); S = FFT(s): ReS = ReA, ImS = ReB.
// 1024-pt DIF: stages 512..64 register-local (running twiddle); ONE
// wave-private LDS transpose re-owns data as p = 16*lane + j; stages 32,16
// via quad-perm shfl_xor (DPP/VALU); stages 8..1 register-local.
// State held as float2 vectors so butterfly add/sub emit v_pk_add_f32.
__global__ __launch_bounds__(256)
void stft_kernel(const float* __restrict__ x, float* __restrict__ out,
                 unsigned long long cap)
{
    __shared__ float uni[OT_SZ];   // [0, 4*1056): per-wave transpose scratch
                                   // (dead after the barrier); then ot tile.

    const int tid  = threadIdx.x;
    const int wv   = tid >> 6;
    const int lane = tid & 63;
    const int tile = blockIdx.x % NTILES;
    const int b    = blockIdx.x / NTILES;
    const int t0   = tile * FPB;

    const float TWO_PI = 6.283185307179586f;

    float sLv, cLv;
    __sincosf(TWO_PI * (float)lane * (1.0f / 1024.0f), &sLv, &cLv);

    const float* xb = x + (size_t)b * T_LEN;
    const int base = (t0 + 2 * wv) * HOP - PAD;
    const bool safe = (base >= 0) && (base + HOP + 1024 < T_LEN);

    f32x2 z[16];

    // ---- load: s[n] = 0.5*w[n]*(x[p+n]+x[p+m]), m=(1024-n)&1023, w[m]=w[n]
    if (safe) {
        #pragma unroll
        for (int r = 0; r < 16; ++r) {
            const int n = (r << 6) | lane;
            const int m = (1024 - n) & 1023;
            const float wh = 0.25f - 0.25f * (CA_[r] * cLv - SA_[r] * sLv);
            z[r].x = wh * (xb[base + n]       + xb[base + m]);
            z[r].y = wh * (xb[base + HOP + n] + xb[base + HOP + m]);
        }
    } else {
        auto rfl = [](int p) {
            p = (p < 0) ? -p : p;
            return (p >= T_LEN) ? (2 * (T_LEN - 1) - p) : p;
        };
        #pragma unroll
        for (int r = 0; r < 16; ++r) {
            const int n = (r << 6) | lane;
            const int m = (1024 - n) & 1023;
            const float wh = 0.25f - 0.25f * (CA_[r] * cLv - SA_[r] * sLv);
            z[r].x = wh * (xb[rfl(base + n)]       + xb[rfl(base + m)]);
            z[r].y = wh * (xb[rfl(base + HOP + n)] + xb[rfl(base + HOP + m)]);
        }
    }

    // running twiddle: w1 = exp(-2pi*i*lane/1024)
    float wr = cLv, wi = -sLv;
#define SQW() { float t_ = wr * wr - wi * wi; wi = 2.0f * wr * wi; wr = t_; }

    // ---- DIF stage h=512: pairs (r, r+8), tw = w1 * C16^r ----
    #pragma unroll
    for (int r = 0; r < 8; ++r) {
        const int v = r + 8;
        f32x2 d = z[r] - z[v];
        z[r] = z[r] + z[v];
        float er = d.x * wr - d.y * wi;
        float ei = d.x * wi + d.y * wr;
        z[v] = mk2(er * CA_[r] + ei * SA_[r], ei * CA_[r] - er * SA_[r]);
    }
    SQW()   // -> w2
    // ---- stage h=256: pairs (8g+k, +4), tw = w2 * C8^k ----
    #pragma unroll
    for (int g = 0; g < 2; ++g)
    #pragma unroll
    for (int k = 0; k < 4; ++k) {
        const int u = (g << 3) + k, v = u + 4;
        f32x2 d = z[u] - z[v];
        z[u] = z[u] + z[v];
        float er = d.x * wr - d.y * wi;
        float ei = d.x * wi + d.y * wr;
        z[v] = mk2(er * CA_[2 * k] + ei * SA_[2 * k], ei * CA_[2 * k] - er * SA_[2 * k]);
    }
    SQW()   // -> w4
    // ---- stage h=128: pairs (4g+k, +2), tw = w4 * C4^k ----
    #pragma unroll
    for (int g = 0; g < 4; ++g)
    #pragma unroll
    for (int k = 0; k < 2; ++k) {
        const int u = (g << 2) + k, v = u + 2;
        f32x2 d = z[u] - z[v];
        z[u] = z[u] + z[v];
        float er = d.x * wr - d.y * wi;
        float ei = d.x * wi + d.y * wr;
        z[v] = mk2(er * CA_[4 * k] + ei * SA_[4 * k], ei * CA_[4 * k] - er * SA_[4 * k]);
    }
    SQW()   // -> w8
    // ---- stage h=64: pairs (u, u+1), tw = w8 ----
    #pragma unroll
    for (int u = 0; u < 16; u += 2) {
        const int v = u + 1;
        f32x2 d = z[u] - z[v];
        z[u] = z[u] + z[v];
        z[v] = mk2(d.x * wr - d.y * wi, d.x * wi + d.y * wr);
    }
#undef SQW

    // ---- wave-private transpose: ownership p=64r+lane -> p=16*lane+j ----
    // x then y sequentially through one 1056-float buffer (in-order DS).
    {
        float* sc = uni + wv * 1056;
        #pragma unroll
        for (int r = 0; r < 16; ++r) sc[SKA((r << 6) | lane)] = z[r].x;
        #pragma unroll
        for (int j = 0; j < 16; ++j) z[j].x = sc[SKA((lane << 4) | j)];
        #pragma unroll
        for (int r = 0; r < 16; ++r) sc[SKA((r << 6) | lane)] = z[r].y;
        #pragma unroll
        for (int j = 0; j < 16; ++j) z[j].y = sc[SKA((lane << 4) | j)];
    }
    __syncthreads();   // scratch dead for ALL waves; uni becomes the ot tile

    // ---- stage h=32: partner lane^2 (p bit5 = lane bit1) ----
    {
        const bool vs  = (lane & 2) != 0;
        const bool odd = (lane & 1) != 0;
        #pragma unroll
        for (int j = 0; j < 16; ++j) {
            f32x2 o = mk2(__shfl_xor(z[j].x, 2), __shfl_xor(z[j].y, 2));
            f32x2 d = o - z[j];                 // other - self
            f32x2 s = z[j] + o;
            float qr = d.x * C64_[j] + d.y * S64_[j];
            float qi = d.y * C64_[j] - d.x * S64_[j];
            float vr = odd ? qi  : qr;          // odd lanes: extra factor -i
            float vi = odd ? -qr : qi;
            z[j] = vs ? mk2(vr, vi) : s;
        }
    }
    // ---- stage h=16: partner lane^1 (p bit4 = lane bit0) ----
    {
        const bool vs = (lane & 1) != 0;
        #pragma unroll
        for (int j = 0; j < 16; ++j) {
            f32x2 o = mk2(__shfl_xor(z[j].x, 1), __shfl_xor(z[j].y, 1));
            f32x2 d = o - z[j];                 // other - self = u - v
            f32x2 s = z[j] + o;
            float qr = d.x * C32_[j] + d.y * S32_[j];
            float qi = d.y * C32_[j] - d.x * S32_[j];
            z[j] = vs ? mk2(qr, qi) : s;
        }
    }
    // ---- stage h=8: pairs (j, j+8), tw = C16^j ----
    #pragma unroll
    for (int j = 0; j < 8; ++j) {
        const int v = j + 8;
        f32x2 d = z[j] - z[v];
        z[j] = z[j] + z[v];
        z[v] = mk2(d.x * CA_[j] + d.y * SA_[j], d.y * CA_[j] - d.x * SA_[j]);
    }
    // ---- stage h=4: pairs (g+j0, +4), tw = C8^j0 = C16^(2j0) ----
    #pragma unroll
    for (int g = 0; g < 16; g += 8)
    #pragma unroll
    for (int j0 = 0; j0 < 4; ++j0) {
        const int u = g + j0, v = u + 4;
        f32x2 d = z[u] - z[v];
        z[u] = z[u] + z[v];
        z[v] = mk2(d.x * CA_[2 * j0] + d.y * SA_[2 * j0],
                   d.y * CA_[2 * j0] - d.x * SA_[2 * j0]);
    }
    // ---- stage h=2: pairs (g+j0, +2), tw = 1 or -i ----
    #pragma unroll
    for (int g = 0; g < 16; g += 4) {
        {   // j0 = 0, tw = 1
            const int u = g, v = g + 2;
            f32x2 d = z[u] - z[v];
            z[u] = z[u] + z[v];
            z[v] = d;
        }
        {   // j0 = 1, tw = -i : d*(-i) = (d.y, -d.x)
            const int u = g + 1, v = g + 3;
            f32x2 d = z[u] - z[v];
            z[u] = z[u] + z[v];
            z[v] = mk2(d.y, -d.x);
        }
    }
    // ---- stage h=1: pairs (u, u+1), tw = 1 ----
    #pragma unroll
    for (int u = 0; u < 16; u += 2) {
        const int v = u + 1;
        f32x2 d = z[u] - z[v];
        z[u] = z[u] + z[v];
        z[v] = d;
    }

    // ---- extract: value (lane, j) = S[f], f = rev4(j)*64 + rev6(lane) ----
    const int m6 = (int)(__brev((unsigned)lane) >> 26);
    #pragma unroll
    for (int jj = 0; jj < 8; ++jj) {
        const int j = jj << 1;                       // even j -> f < 512
        const int f = (R4_[j] << 6) + m6;
        uni[OTI(f) + 2 * wv]     = z[j].x;           // Re S = Re A[f]
        uni[OTI(f) + 2 * wv + 1] = z[j].y;           // Im S = Re B[f]
    }
    if (lane == 0) {                                 // j=1: rev4=8 -> f=512
        uni[OTI(512) + 2 * wv]     = z[1].x;
        uni[OTI(512) + 2 * wv + 1] = z[1].y;
    }

    __syncthreads();

    // ---- flush: 8 consecutive t per f row (32B segments) ----
    #pragma unroll
    for (int it = 0; it < 17; ++it) {
        const int idx = tid + it * 256;
        if (idx < N_FREQ * FPB) {
            const int f = idx >> 3, c = idx & 7;
            const int t = t0 + c;
            if (t < N_FRAMES) {
                unsigned long long o =
                    (unsigned long long)(b * N_FREQ + f) * N_FRAMES
                    + (unsigned long long)t;
                if (o < cap) out[o] = uni[OTI(f) + c];
            }
        }
    }
}

extern "C" void kernel_launch(void* const* d_in, const int* in_sizes, int n_in,
                              void* d_out, int out_size, void* d_ws, size_t ws_size,
                              hipStream_t stream)
{
    const float* x = (const float*)d_in[0];
    float* out = (float*)d_out;
    if (!x || !out || out_size <= 0) return;

    unsigned long long cap = (unsigned long long)(long long)out_size;

    dim3 grid(BATCH * NTILES);   // 2064 blocks
    dim3 block(256);
    stft_kernel<<<grid, block, 0, stream>>>(x, out, cap);
}

// Round 16
// 33.114 us; speedup vs baseline: 1.1431x; 1.1431x over previous
//
#include <hip/hip_runtime.h>

#define N_FFT    1024
#define HOP      256
#define BATCH    16
#define T_LEN    262144
#define PAD      512
#define N_FRAMES 1025
#define N_FREQ   513
#define FPB      8
#define NTILES   129        // ceil(1025/8)

// output staging tile: stride 9 + skew (conflict-free extract, ~2-way flush)
#define OTI(f) ((f) * 9 + ((f) >> 4))
#define OT_SZ  (OTI(512) + 9)          // 4649 floats
// skew for the wave-private transpose scratch (2-way max on write & read)
#define SKA(p) ((p) + ((p) >> 5))

__device__ constexpr int   R4_[16] = {0,8,4,12,2,10,6,14,1,9,5,13,3,11,7,15}; // rev4
__device__ constexpr float CA_[16] = {   // cos(2*pi*k/16)
     1.0f,           0.92387953251f,  0.70710678119f,  0.38268343236f,
     0.0f,          -0.38268343236f, -0.70710678119f, -0.92387953251f,
    -1.0f,          -0.92387953251f, -0.70710678119f, -0.38268343236f,
     0.0f,           0.38268343236f,  0.70710678119f,  0.92387953251f};
__device__ constexpr float SA_[16] = {   // sin(2*pi*k/16)
     0.0f,           0.38268343236f,  0.70710678119f,  0.92387953251f,
     1.0f,           0.92387953251f,  0.70710678119f,  0.38268343236f,
     0.0f,          -0.38268343236f, -0.70710678119f, -0.92387953251f,
    -1.0f,          -0.92387953251f, -0.70710678119f, -0.38268343236f};
__device__ constexpr float C32_[16] = {  // cos(2*pi*j/32)
     1.0f,           0.98078528040f,  0.92387953251f,  0.83146961230f,
     0.70710678119f, 0.55557023302f,  0.38268343236f,  0.19509032202f,
     0.0f,          -0.19509032202f, -0.38268343236f, -0.55557023302f,
    -0.70710678119f,-0.83146961230f, -0.92387953251f, -0.98078528040f};
__device__ constexpr float S32_[16] = {  // sin(2*pi*j/32)
     0.0f,           0.19509032202f,  0.38268343236f,  0.55557023302f,
     0.70710678119f, 0.83146961230f,  0.92387953251f,  0.98078528040f,
     1.0f,           0.98078528040f,  0.92387953251f,  0.83146961230f,
     0.70710678119f, 0.55557023302f,  0.38268343236f,  0.19509032202f};
__device__ constexpr float C64_[16] = {  // cos(2*pi*j/64)
     1.0f,           0.99518472667f,  0.98078528040f,  0.95694033573f,
     0.92387953251f, 0.88192126435f,  0.83146961230f,  0.77301045336f,
     0.70710678119f, 0.63439328416f,  0.55557023302f,  0.47139673683f,
     0.38268343236f, 0.29028467725f,  0.19509032202f,  0.09801714033f};
__device__ constexpr float S64_[16] = {  // sin(2*pi*j/64)
     0.0f,           0.09801714033f,  0.19509032202f,  0.29028467725f,
     0.38268343236f, 0.47139673683f,  0.55557023302f,  0.63439328416f,
     0.70710678119f, 0.77301045336f,  0.83146961230f,  0.88192126435f,
     0.92387953251f, 0.95694033573f,  0.98078528040f,  0.99518472667f};

// Block = (batch, 8-frame tile), 256 threads = 4 waves; wave wv owns frames
// (t0+2wv, t0+2wv+1) packed via the symmetric-sequence trick:
// s[n] = 0.5*w[n]*(x[p+n]+x[p+m]); S = FFT(s): ReS = ReA, ImS = ReB.
// 1024-pt DIF with RADIX-4 fused stage pairs: (512+256),(128+64) reg-local
// with running twiddles; ONE wave-private LDS transpose (p=64r+lane ->
// p=16*lane+j); (32,16) via quad-perm shfl_xor sigma-fma; (8+4),(2+1)
// reg-local with constant twiddles.
__global__ __launch_bounds__(256)
void stft_kernel(const float* __restrict__ x, float* __restrict__ out,
                 unsigned long long cap)
{
    __shared__ float uni[OT_SZ];   // [0, 4*1056): per-wave transpose scratch
                                   // (dead after the barrier); then ot tile.

    const int tid  = threadIdx.x;
    const int wv   = tid >> 6;
    const int lane = tid & 63;
    const int tile = blockIdx.x % NTILES;
    const int b    = blockIdx.x / NTILES;
    const int t0   = tile * FPB;

    const float TWO_PI = 6.283185307179586f;

    float sLv, cLv;
    sincosf(TWO_PI * (float)lane * (1.0f / 1024.0f), &sLv, &cLv);

    const float* xb = x + (size_t)b * T_LEN;
    const int base = (t0 + 2 * wv) * HOP - PAD;
    const bool safe = (base >= 0) && (base + HOP + 1024 < T_LEN);

    float sr_[16], si_[16];

    // ---- load: s[n] = 0.5*w[n]*(x[p+n]+x[p+m]), m=(1024-n)&1023, w[m]=w[n]
    if (safe) {
        #pragma unroll
        for (int r = 0; r < 16; ++r) {
            const int n = (r << 6) | lane;
            const int m = (1024 - n) & 1023;
            const float wh = 0.25f - 0.25f * (CA_[r] * cLv - SA_[r] * sLv);
            sr_[r] = wh * (xb[base + n]       + xb[base + m]);
            si_[r] = wh * (xb[base + HOP + n] + xb[base + HOP + m]);
        }
    } else {
        auto rfl = [](int p) {
            p = (p < 0) ? -p : p;
            return (p >= T_LEN) ? (2 * (T_LEN - 1) - p) : p;
        };
        #pragma unroll
        for (int r = 0; r < 16; ++r) {
            const int n = (r << 6) | lane;
            const int m = (1024 - n) & 1023;
            const float wh = 0.25f - 0.25f * (CA_[r] * cLv - SA_[r] * sLv);
            sr_[r] = wh * (xb[rfl(base + n)]       + xb[rfl(base + m)]);
            si_[r] = wh * (xb[rfl(base + HOP + n)] + xb[rfl(base + HOP + m)]);
        }
    }

    // twiddles: w1 = exp(-2pi*i*lane/1024); w2 = w1^2
    const float w1r = cLv, w1i = -sLv;
    const float w2r = w1r * w1r - w1i * w1i;
    const float w2i = 2.0f * w1r * w1i;

    // ---- FUSED stages h=512 + h=256 (radix-4): quads {r, r+4, r+8, r+12} ----
    #pragma unroll
    for (int r = 0; r < 4; ++r) {
        float s0r = sr_[r]     + sr_[r + 8],  s0i = si_[r]     + si_[r + 8];
        float d0r = sr_[r]     - sr_[r + 8],  d0i = si_[r]     - si_[r + 8];
        float s1r = sr_[r + 4] + sr_[r + 12], s1i = si_[r + 4] + si_[r + 12];
        float d1r = sr_[r + 4] - sr_[r + 12], d1i = si_[r + 4] - si_[r + 12];
        sr_[r] = s0r + s1r;  si_[r] = s0i + s1i;
        float t01r = s0r - s1r, t01i = s0i - s1i;
        // u2 = w2 * E8(r);  u1 = w1 * E16(r)
        float u2r = w2r * CA_[2 * r] + w2i * SA_[2 * r];
        float u2i = w2i * CA_[2 * r] - w2r * SA_[2 * r];
        float u1r = w1r * CA_[r] + w1i * SA_[r];
        float u1i = w1i * CA_[r] - w1r * SA_[r];
        sr_[r + 4] = t01r * u2r - t01i * u2i;
        si_[r + 4] = t01r * u2i + t01i * u2r;
        float emr = d0r + d1i, emi = d0i - d1r;   // d0 - i*d1
        float epr = d0r - d1i, epi = d0i + d1r;   // d0 + i*d1
        sr_[r + 8] = emr * u1r - emi * u1i;
        si_[r + 8] = emr * u1i + emi * u1r;
        float vr = epr * u1r - epi * u1i;
        float vi = epr * u1i + epi * u1r;
        sr_[r + 12] = vr * u2r - vi * u2i;
        si_[r + 12] = vr * u2i + vi * u2r;
    }

    // w4 = w2^2; w8 = w4^2; w12 = w4*w8
    const float w4r = w2r * w2r - w2i * w2i;
    const float w4i = 2.0f * w2r * w2i;
    const float w8r = w4r * w4r - w4i * w4i;
    const float w8i = 2.0f * w4r * w4i;
    const float wcr = w4r * w8r - w4i * w8i;
    const float wci = w4r * w8i + w4i * w8r;

    // ---- FUSED stages h=128 + h=64 (radix-4): quads {4g, 4g+1, 4g+2, 4g+3} ----
    #pragma unroll
    for (int g = 0; g < 4; ++g) {
        const int q = g << 2;
        float s0r = sr_[q]     + sr_[q + 2], s0i = si_[q]     + si_[q + 2];
        float d0r = sr_[q]     - sr_[q + 2], d0i = si_[q]     - si_[q + 2];
        float s1r = sr_[q + 1] + sr_[q + 3], s1i = si_[q + 1] + si_[q + 3];
        float d1r = sr_[q + 1] - sr_[q + 3], d1i = si_[q + 1] - si_[q + 3];
        sr_[q] = s0r + s1r;  si_[q] = s0i + s1i;
        float tr = s0r - s1r, ti = s0i - s1i;
        sr_[q + 1] = tr * w8r - ti * w8i;
        si_[q + 1] = tr * w8i + ti * w8r;
        float emr = d0r + d1i, emi = d0i - d1r;
        float epr = d0r - d1i, epi = d0i + d1r;
        sr_[q + 2] = emr * w4r - emi * w4i;
        si_[q + 2] = emr * w4i + emi * w4r;
        sr_[q + 3] = epr * wcr - epi * wci;
        si_[q + 3] = epr * wci + epi * wcr;
    }

    // ---- wave-private transpose: ownership p=64r+lane -> p=16*lane+j ----
    {
        float* sc = uni + wv * 1056;
        #pragma unroll
        for (int r = 0; r < 16; ++r) sc[SKA((r << 6) | lane)] = sr_[r];
        #pragma unroll
        for (int j = 0; j < 16; ++j) sr_[j] = sc[SKA((lane << 4) | j)];
        #pragma unroll
        for (int r = 0; r < 16; ++r) sc[SKA((r << 6) | lane)] = si_[r];
        #pragma unroll
        for (int j = 0; j < 16; ++j) si_[j] = sc[SKA((lane << 4) | j)];
    }
    __syncthreads();   // scratch dead for ALL waves; uni becomes the ot tile

    // ---- stage h=32: partner lane^2; sigma-fma + const-folded odd(-i) ----
    {
        const bool vs  = (lane & 2) != 0;
        const bool odd = (lane & 1) != 0;
        const float sg = vs ? -1.0f : 1.0f;
        #pragma unroll
        for (int j = 0; j < 16; ++j) {
            float orr = __shfl_xor(sr_[j], 2);
            float oii = __shfl_xor(si_[j], 2);
            float tr = fmaf(sg, sr_[j], orr);       // lo: s+o ; hi: o-s
            float ti = fmaf(sg, si_[j], oii);
            const float cj = odd ? -S64_[j] : C64_[j];
            const float sj = odd ?  C64_[j] : S64_[j];
            float qr = tr * cj + ti * sj;
            float qi = ti * cj - tr * sj;
            sr_[j] = vs ? qr : tr;
            si_[j] = vs ? qi : ti;
        }
    }
    // ---- stage h=16: partner lane^1; sigma-fma ----
    {
        const bool vs = (lane & 1) != 0;
        const float sg = vs ? -1.0f : 1.0f;
        #pragma unroll
        for (int j = 0; j < 16; ++j) {
            float orr = __shfl_xor(sr_[j], 1);
            float oii = __shfl_xor(si_[j], 1);
            float tr = fmaf(sg, sr_[j], orr);
            float ti = fmaf(sg, si_[j], oii);
            float qr = tr * C32_[j] + ti * S32_[j];
            float qi = ti * C32_[j] - tr * S32_[j];
            sr_[j] = vs ? qr : tr;
            si_[j] = vs ? qi : ti;
        }
    }

    // ---- FUSED stages h=8 + h=4 (radix-4, const tw): quads {j,j+4,j+8,j+12} ----
    #pragma unroll
    for (int j = 0; j < 4; ++j) {
        float s0r = sr_[j]     + sr_[j + 8],  s0i = si_[j]     + si_[j + 8];
        float d0r = sr_[j]     - sr_[j + 8],  d0i = si_[j]     - si_[j + 8];
        float s1r = sr_[j + 4] + sr_[j + 12], s1i = si_[j + 4] + si_[j + 12];
        float d1r = sr_[j + 4] - sr_[j + 12], d1i = si_[j + 4] - si_[j + 12];
        sr_[j] = s0r + s1r;  si_[j] = s0i + s1i;
        float tr = s0r - s1r, ti = s0i - s1i;
        sr_[j + 4] = tr * CA_[2 * j] + ti * SA_[2 * j];       // * E8(j)
        si_[j + 4] = ti * CA_[2 * j] - tr * SA_[2 * j];
        float emr = d0r + d1i, emi = d0i - d1r;
        float epr = d0r - d1i, epi = d0i + d1r;
        sr_[j + 8] = emr * CA_[j] + emi * SA_[j];             // * E16(j)
        si_[j + 8] = emi * CA_[j] - emr * SA_[j];
        sr_[j + 12] = epr * CA_[3 * j] + epi * SA_[3 * j];    // * E16(3j)
        si_[j + 12] = epi * CA_[3 * j] - epr * SA_[3 * j];
    }
    // ---- FUSED stages h=2 + h=1 (radix-4, trivial tw): quads {g..g+3} ----
    #pragma unroll
    for (int g = 0; g < 16; g += 4) {
        float s0r = sr_[g]     + sr_[g + 2], s0i = si_[g]     + si_[g + 2];
        float d0r = sr_[g]     - sr_[g + 2], d0i = si_[g]     - si_[g + 2];
        float s1r = sr_[g + 1] + sr_[g + 3], s1i = si_[g + 1] + si_[g + 3];
        float d1r = sr_[g + 1] - sr_[g + 3], d1i = si_[g + 1] - si_[g + 3];
        sr_[g]     = s0r + s1r;  si_[g]     = s0i + s1i;
        sr_[g + 1] = s0r - s1r;  si_[g + 1] = s0i - s1i;
        sr_[g + 2] = d0r + d1i;  si_[g + 2] = d0i - d1r;   // d0 - i*d1
        sr_[g + 3] = d0r - d1i;  si_[g + 3] = d0i + d1r;   // d0 + i*d1
    }

    // ---- extract: value (lane, j) = S[f], f = rev4(j)*64 + rev6(lane) ----
    // OTI(f) = 580*R4[j] + (9*m6 + (m6>>4)); literal per-j offsets.
    const int m6 = (int)(__brev((unsigned)lane) >> 26);
    const int obase = 9 * m6 + (m6 >> 4) + 2 * wv;
    #pragma unroll
    for (int jj = 0; jj < 8; ++jj) {
        const int j = jj << 1;                       // even j -> f < 512
        uni[obase + 580 * R4_[j]]     = sr_[j];      // Re S = Re A[f]
        uni[obase + 580 * R4_[j] + 1] = si_[j];      // Im S = Re B[f]
    }
    if (lane == 0) {                                 // j=1: rev4=8 -> f=512
        uni[OTI(512) + 2 * wv]     = sr_[1];
        uni[OTI(512) + 2 * wv + 1] = si_[1];
    }

    __syncthreads();

    // ---- flush: strength-reduced; f = f0 + 32*it, oti += 290, o += 32*1025 ----
    {
        const int c  = tid & 7;
        const int f0 = tid >> 3;                         // 0..31
        const bool tok = (t0 + c) < N_FRAMES;            // lane-constant
        unsigned long long o =
            (unsigned long long)(b * N_FREQ + f0) * N_FRAMES
            + (unsigned long long)(t0 + c);
        int oti = f0 * 9 + (f0 >> 4);
        #pragma unroll
        for (int it = 0; it < 17; ++it) {
            const int f = f0 + 32 * it;
            if (f < N_FREQ && tok && o < cap) {
                out[o] = uni[oti + c];
            }
            o   += 32ull * N_FRAMES;
            oti += 290;                                  // 32*9 + 2
        }
    }
}

extern "C" void kernel_launch(void* const* d_in, const int* in_sizes, int n_in,
                              void* d_out, int out_size, void* d_ws, size_t ws_size,
                              hipStream_t stream)
{
    const float* x = (const float*)d_in[0];
    float* out = (float*)d_out;
    if (!x || !out || out_size <= 0) return;

    unsigned long long cap = (unsigned long long)(long long)out_size;

    dim3 grid(BATCH * NTILES);   // 2064 blocks
    dim3 block(256);
    stft_kernel<<<grid, block, 0, stream>>>(x, out, cap);
}